// Round 1
// baseline (3779.725 us; speedup 1.0000x reference)
//
#include <hip/hip_runtime.h>
#include <math.h>

// Grid-RNN (WhileOpGridLSTMNet): DEPTH=2, SRC=TRG=32, B=32, H=256
// out[d][i][j][c][b][h], c=0:HX, c=1:HY
#define SRCN 32
#define TRGN 32
#define BN   32
#define HN   256
#define BH   (BN*HN)          // 8192 floats per (cell,channel)
#define CELL (2*BH)           // 16384 floats per cell
#define DSZ  (SRCN*TRGN*CELL) // 16777216 floats per depth

// ---------------------------------------------------------------------------
// proj0: Xp0[i] = source[i] @ W0 ; Yp0[j] = target[j] @ W0
// grid = 64 slices * 4 col-tiles, block = 256
// ---------------------------------------------------------------------------
__global__ __launch_bounds__(256) void proj0_kernel(
    const float* __restrict__ src, const float* __restrict__ trg,
    const float* __restrict__ W0,
    float* __restrict__ Xp0, float* __restrict__ Yp0)
{
    __shared__ float xs[BH]; // 32 KB
    int blk  = blockIdx.x >> 2;
    int tile = blockIdx.x & 3;
    const float* X;
    float* P;
    if (blk < SRCN) { X = src + blk * BH;          P = Xp0 + blk * BH; }
    else            { X = trg + (blk - SRCN) * BH; P = Yp0 + (blk - SRCN) * BH; }
    int tid = threadIdx.x;
    {
        const float4* x4 = (const float4*)X;
        float4* s4 = (float4*)xs;
#pragma unroll
        for (int r = 0; r < 8; ++r) s4[tid + r * 256] = x4[tid + r * 256];
    }
    __syncthreads();
    int h  = tile * 64 + (tid & 63);
    int bg = tid >> 6; // wave-uniform
    float acc[8] = {0, 0, 0, 0, 0, 0, 0, 0};
    for (int k = 0; k < HN; k += 4) {
        float w0 = W0[(k + 0) * HN + h];
        float w1 = W0[(k + 1) * HN + h];
        float w2 = W0[(k + 2) * HN + h];
        float w3 = W0[(k + 3) * HN + h];
#pragma unroll
        for (int bb = 0; bb < 8; ++bb) {
            int b = bg * 8 + bb;
            float4 xv = *(const float4*)&xs[b * HN + k];
            acc[bb] += xv.x * w0 + xv.y * w1 + xv.z * w2 + xv.w * w3;
        }
    }
#pragma unroll
    for (int bb = 0; bb < 8; ++bb) {
        int b = bg * 8 + bb;
        P[b * HN + h] = acc[bb];
    }
}

// ---------------------------------------------------------------------------
// proj1: Xp1[i][j] = HX0[i][j] @ W1 -> out[1][i][j][0]
//        Yp1[i][j] = HY0[i][j] @ W1 -> out[1][i][j][1]
// grid = 1024 cells * 4 col-tiles, block = 256
// ---------------------------------------------------------------------------
__global__ __launch_bounds__(256) void proj1_kernel(
    float* __restrict__ out, const float* __restrict__ W1)
{
    __shared__ float hxs[BH]; // 32 KB
    __shared__ float hys[BH]; // 32 KB
    int cell = blockIdx.x >> 2;
    int tile = blockIdx.x & 3;
    const float* hx0 = out + (size_t)cell * CELL; // out[0][i][j][0]
    const float* hy0 = hx0 + BH;
    float* xp1 = out + (size_t)DSZ + (size_t)cell * CELL;
    float* yp1 = xp1 + BH;
    int tid = threadIdx.x;
    {
        const float4* a4 = (const float4*)hx0;
        const float4* b4 = (const float4*)hy0;
        float4* sa = (float4*)hxs;
        float4* sb = (float4*)hys;
#pragma unroll
        for (int r = 0; r < 8; ++r) {
            sa[tid + r * 256] = a4[tid + r * 256];
            sb[tid + r * 256] = b4[tid + r * 256];
        }
    }
    __syncthreads();
    int h  = tile * 64 + (tid & 63);
    int bg = tid >> 6;
    float ax[8] = {0, 0, 0, 0, 0, 0, 0, 0};
    float ay[8] = {0, 0, 0, 0, 0, 0, 0, 0};
    for (int k = 0; k < HN; k += 4) {
        float w0 = W1[(k + 0) * HN + h];
        float w1 = W1[(k + 1) * HN + h];
        float w2 = W1[(k + 2) * HN + h];
        float w3 = W1[(k + 3) * HN + h];
#pragma unroll
        for (int bb = 0; bb < 8; ++bb) {
            int b = bg * 8 + bb;
            float4 xv = *(const float4*)&hxs[b * HN + k];
            float4 yv = *(const float4*)&hys[b * HN + k];
            ax[bb] += xv.x * w0 + xv.y * w1 + xv.z * w2 + xv.w * w3;
            ay[bb] += yv.x * w0 + yv.y * w1 + yv.z * w2 + yv.w * w3;
        }
    }
#pragma unroll
    for (int bb = 0; bb < 8; ++bb) {
        int b = bg * 8 + bb;
        xp1[b * HN + h] = ax[bb];
        yp1[b * HN + h] = ay[bb];
    }
}

// ---------------------------------------------------------------------------
// diag: process all cells on anti-diagonal t of layer d.
//   temp = sx@Ux + ph@Uy + bias ; hx = tanh(xp+temp) ; hy = tanh(yp+temp)
//   sx = HX[i-1][j] (0 if i==0), ph = HX[i][j-1] (0 if j==0)
//   d==0: xp = Xp0[i], yp = Yp0[j]
//   d==1: xp/yp read in-place from out[1][i][j][0/1], overwritten with hx/hy
// grid = nc * 4 col-tiles, block = 256
// ---------------------------------------------------------------------------
__global__ __launch_bounds__(256) void diag_kernel(
    float* out, const float* __restrict__ U,
    const float* __restrict__ bias,
    const float* __restrict__ Xp0, const float* __restrict__ Yp0,
    int d, int t)
{
    __shared__ float sxs[BH]; // 32 KB
    __shared__ float phs[BH]; // 32 KB
    int c    = blockIdx.x >> 2;
    int tile = blockIdx.x & 3;
    int i0 = t - (TRGN - 1); if (i0 < 0) i0 = 0;
    int i = i0 + c;
    int j = t - i;

    const float* Ux = U + d * (2 * HN * HN);
    const float* Uy = Ux + HN * HN;
    float* outD = out + (size_t)d * DSZ;
    const float* sx = (i > 0) ? outD + (size_t)((i - 1) * TRGN + j) * CELL : nullptr;
    const float* ph = (j > 0) ? outD + (size_t)(i * TRGN + (j - 1)) * CELL : nullptr;
    float* oHX = outD + (size_t)(i * TRGN + j) * CELL;
    float* oHY = oHX + BH;
    const float* xp = d ? oHX : (Xp0 + i * BH);
    const float* yp = d ? oHY : (Yp0 + j * BH);
    const float* bd = bias + d * HN;

    int tid = threadIdx.x;
    {
        const float4* s4 = (const float4*)sx;
        const float4* p4 = (const float4*)ph;
        float4* d1 = (float4*)sxs;
        float4* d2 = (float4*)phs;
        float4 z = make_float4(0.f, 0.f, 0.f, 0.f);
#pragma unroll
        for (int r = 0; r < 8; ++r) {
            int idx = tid + r * 256;
            d1[idx] = sx ? s4[idx] : z;
            d2[idx] = ph ? p4[idx] : z;
        }
    }
    __syncthreads();

    int h  = tile * 64 + (tid & 63);
    int bg = tid >> 6; // wave-uniform -> LDS broadcast reads below
    float acc[8] = {0, 0, 0, 0, 0, 0, 0, 0};
    for (int k = 0; k < HN; k += 4) {
        float ux0 = Ux[(k + 0) * HN + h];
        float ux1 = Ux[(k + 1) * HN + h];
        float ux2 = Ux[(k + 2) * HN + h];
        float ux3 = Ux[(k + 3) * HN + h];
        float uy0 = Uy[(k + 0) * HN + h];
        float uy1 = Uy[(k + 1) * HN + h];
        float uy2 = Uy[(k + 2) * HN + h];
        float uy3 = Uy[(k + 3) * HN + h];
#pragma unroll
        for (int bb = 0; bb < 8; ++bb) {
            int b = bg * 8 + bb;
            float4 sv = *(const float4*)&sxs[b * HN + k];
            float4 pv = *(const float4*)&phs[b * HN + k];
            acc[bb] += sv.x * ux0 + sv.y * ux1 + sv.z * ux2 + sv.w * ux3
                     + pv.x * uy0 + pv.y * uy1 + pv.z * uy2 + pv.w * uy3;
        }
    }
    float bv = bd[h];
#pragma unroll
    for (int bb = 0; bb < 8; ++bb) {
        int b = bg * 8 + bb;
        float temp = acc[bb] + bv;
        float hxv = tanhf(xp[b * HN + h] + temp);
        float hyv = tanhf(yp[b * HN + h] + temp);
        oHX[b * HN + h] = hxv;
        oHY[b * HN + h] = hyv;
    }
}

// ---------------------------------------------------------------------------
extern "C" void kernel_launch(void* const* d_in, const int* in_sizes, int n_in,
                              void* d_out, int out_size, void* d_ws, size_t ws_size,
                              hipStream_t stream)
{
    const float* source = (const float*)d_in[0];
    const float* target = (const float*)d_in[1];
    const float* W      = (const float*)d_in[2]; // [2][256][256]
    const float* U      = (const float*)d_in[3]; // [2][512][256]
    const float* bias   = (const float*)d_in[4]; // [2][1][256]
    float* out = (float*)d_out;

    // Scratch for layer-0 projections lives at the start of the layer-1
    // output region (overwritten later by proj1 after layer-0 completes).
    float* Xp0 = out + DSZ;           // 32*32*256 floats
    float* Yp0 = Xp0 + SRCN * BH;     // 32*32*256 floats

    proj0_kernel<<<dim3(64 * 4), dim3(256), 0, stream>>>(source, target, W, Xp0, Yp0);

    for (int t = 0; t < SRCN + TRGN - 1; ++t) {
        int nc = t + 1;
        if (nc > 63 - t) nc = 63 - t;
        if (nc > 32) nc = 32;
        diag_kernel<<<dim3(nc * 4), dim3(256), 0, stream>>>(out, U, bias, Xp0, Yp0, 0, t);
    }

    proj1_kernel<<<dim3(1024 * 4), dim3(256), 0, stream>>>(out, W + HN * HN);

    for (int t = 0; t < SRCN + TRGN - 1; ++t) {
        int nc = t + 1;
        if (nc > 63 - t) nc = 63 - t;
        if (nc > 32) nc = 32;
        diag_kernel<<<dim3(nc * 4), dim3(256), 0, stream>>>(out, U, bias, nullptr, nullptr, 1, t);
    }
}